// Round 1
// baseline (7204.097 us; speedup 1.0000x reference)
//
#include <hip/hip_runtime.h>
#include <hip/hip_bf16.h>
#include <stdint.h>

#define KDIM 1024
#define NROW 4096
#define NCOL 4096
#define INFV 1e30f
#define BM 128
#define BK 32

typedef __bf16 bf16x8 __attribute__((ext_vector_type(8)));
typedef float f32x4 __attribute__((ext_vector_type(4)));

__device__ __forceinline__ float bf2f(unsigned short u) {
    return __uint_as_float(((unsigned int)u) << 16);
}
__device__ __forceinline__ unsigned short f2bf(float f) {
    __hip_bfloat16 h = __float2bfloat16(f);
    return *reinterpret_cast<unsigned short*>(&h);
}

// ---------------------------------------------------------------------------
// Kernel 1: row-normalize both trajectories, emit bf16
// ---------------------------------------------------------------------------
__global__ __launch_bounds__(256) void normalize_bf16(
    const float* __restrict__ t1, const float* __restrict__ t2,
    unsigned short* __restrict__ o1, unsigned short* __restrict__ o2)
{
    int b = blockIdx.x;
    int t = threadIdx.x;
    const float* src;
    unsigned short* dst;
    if (b < NROW) { src = t1 + (size_t)b * KDIM;          dst = o1 + (size_t)b * KDIM; }
    else          { src = t2 + (size_t)(b - NROW) * KDIM; dst = o2 + (size_t)(b - NROW) * KDIM; }

    float4 v = reinterpret_cast<const float4*>(src)[t];
    float ss = v.x * v.x + v.y * v.y + v.z * v.z + v.w * v.w;
    #pragma unroll
    for (int d = 32; d >= 1; d >>= 1) ss += __shfl_xor(ss, d, 64);

    __shared__ float wsum[4];
    int wave = t >> 6;
    if ((t & 63) == 0) wsum[wave] = ss;
    __syncthreads();
    float inv = 1.0f / (sqrtf(wsum[0] + wsum[1] + wsum[2] + wsum[3]) + 1e-8f);

    ushort4 o;
    o.x = f2bf(v.x * inv);
    o.y = f2bf(v.y * inv);
    o.z = f2bf(v.z * inv);
    o.w = f2bf(v.w * inv);
    reinterpret_cast<ushort4*>(dst)[t] = o;
}

// ---------------------------------------------------------------------------
// Kernel 2: cost[i][j] = 1 - dot(t1n[i], t2n[j])  (bf16 in, bf16 out)
// 128x128 tile, BK=32, 4 waves each owning a 64x64 quadrant (4x4 of 16x16).
// Register-staged LDS (correctness-first; global_load_lds upgrade later).
// ---------------------------------------------------------------------------
__global__ __launch_bounds__(256) void gemm_cost(
    const unsigned short* __restrict__ A,   // t1n [4096][1024]
    const unsigned short* __restrict__ B,   // t2n [4096][1024]
    unsigned short* __restrict__ C)         // cost bf16 [4096][4096]
{
    __shared__ __align__(16) unsigned short As[BM * BK];
    __shared__ __align__(16) unsigned short Bs[BM * BK];

    int t    = threadIdx.x;
    int lane = t & 63;
    int wave = t >> 6;
    int i0   = blockIdx.y * BM;
    int j0   = blockIdx.x * BM;

    f32x4 acc[4][4];
    f32x4 zero = {0.f, 0.f, 0.f, 0.f};
    #pragma unroll
    for (int m = 0; m < 4; ++m)
        #pragma unroll
        for (int n = 0; n < 4; ++n) acc[m][n] = zero;

    int frow = lane & 15;          // row within 16x16 fragment
    int fk   = (lane >> 4) * 8;    // k offset within fragment
    int wr   = (wave >> 1) * 64;   // wave quadrant row
    int wc   = (wave & 1) * 64;    // wave quadrant col

    int srow = t >> 2;             // staging row (round 0)
    int scb  = (t & 3) * 8;        // staging k sub-block (ushorts)

    uint4 ra0, ra1, rb0, rb1;
    {
        const unsigned short* a0 = A + (size_t)(i0 + srow) * KDIM + scb;
        const unsigned short* a1 = A + (size_t)(i0 + 64 + srow) * KDIM + scb;
        const unsigned short* b0 = B + (size_t)(j0 + srow) * KDIM + scb;
        const unsigned short* b1 = B + (size_t)(j0 + 64 + srow) * KDIM + scb;
        ra0 = *reinterpret_cast<const uint4*>(a0);
        ra1 = *reinterpret_cast<const uint4*>(a1);
        rb0 = *reinterpret_cast<const uint4*>(b0);
        rb1 = *reinterpret_cast<const uint4*>(b1);
    }

    for (int k0 = 0; k0 < KDIM; k0 += BK) {
        __syncthreads();   // previous iteration's LDS reads complete
        *reinterpret_cast<uint4*>(As + (size_t)t * 8)         = ra0;
        *reinterpret_cast<uint4*>(As + (size_t)(256 + t) * 8) = ra1;
        *reinterpret_cast<uint4*>(Bs + (size_t)t * 8)         = rb0;
        *reinterpret_cast<uint4*>(Bs + (size_t)(256 + t) * 8) = rb1;
        __syncthreads();

        if (k0 + BK < KDIM) {   // prefetch next K-step (overlaps MFMA below)
            int kn = k0 + BK;
            ra0 = *reinterpret_cast<const uint4*>(A + (size_t)(i0 + srow) * KDIM + kn + scb);
            ra1 = *reinterpret_cast<const uint4*>(A + (size_t)(i0 + 64 + srow) * KDIM + kn + scb);
            rb0 = *reinterpret_cast<const uint4*>(B + (size_t)(j0 + srow) * KDIM + kn + scb);
            rb1 = *reinterpret_cast<const uint4*>(B + (size_t)(j0 + 64 + srow) * KDIM + kn + scb);
        }

        bf16x8 af[4], bfr[4];
        #pragma unroll
        for (int m = 0; m < 4; ++m)
            af[m] = *reinterpret_cast<const bf16x8*>(As + (wr + m * 16 + frow) * BK + fk);
        #pragma unroll
        for (int n = 0; n < 4; ++n)
            bfr[n] = *reinterpret_cast<const bf16x8*>(Bs + (wc + n * 16 + frow) * BK + fk);

        #pragma unroll
        for (int m = 0; m < 4; ++m)
            #pragma unroll
            for (int n = 0; n < 4; ++n)
                acc[m][n] = __builtin_amdgcn_mfma_f32_16x16x32_bf16(af[m], bfr[n], acc[m][n], 0, 0, 0);
    }

    // Epilogue: C/D layout col=lane&15, row=(lane>>4)*4+q  [m89-verified]
    int crow = (lane >> 4) * 4;
    int ccol = lane & 15;
    #pragma unroll
    for (int m = 0; m < 4; ++m)
        #pragma unroll
        for (int n = 0; n < 4; ++n) {
            size_t base = (size_t)(i0 + wr + m * 16 + crow) * NCOL + (j0 + wc + n * 16 + ccol);
            #pragma unroll
            for (int q = 0; q < 4; ++q)
                C[base + (size_t)q * NCOL] = f2bf(1.0f - acc[m][n][q]);
        }
}

// ---------------------------------------------------------------------------
// Kernel 3: DTW DP, single workgroup, one (sum,min) block scan per row.
//   D[i][j] = min_{k<=j} ( a[k] + sum_{l=k+1..j} c[l] ),
//   a[j] = c[j] + min(Dprev[j], Dprev[j-1])   (with 0/INF sentinels).
// Pair scan: x_j=(c_j, a_j), (A o B) = (sA+sB, min(mA+sB, mB)); D[j]=m.
// ---------------------------------------------------------------------------
__global__ __launch_bounds__(1024) void dtw_kernel(const unsigned short* __restrict__ cost,
                                                   float* __restrict__ out)
{
    __shared__ float Dprev[NCOL];
    __shared__ float2 wpair[16];
    int t    = threadIdx.x;
    int lane = t & 63;
    int wave = t >> 6;

    for (int j = t; j < NCOL; j += 1024) Dprev[j] = INFV;
    __syncthreads();

    ushort4 cb0 = reinterpret_cast<const ushort4*>(cost)[t];
    ushort4 cb1 = reinterpret_cast<const ushort4*>(cost + NCOL)[t];

    float Dlast = 0.0f;
    for (int i = 0; i < NROW; ++i) {
        ushort4 cu = (i & 1) ? cb1 : cb0;
        float c0 = bf2f(cu.x), c1 = bf2f(cu.y), c2 = bf2f(cu.z), c3 = bf2f(cu.w);
        if (i + 2 < NROW) {   // prefetch 2 rows ahead
            ushort4 nx = reinterpret_cast<const ushort4*>(cost + (size_t)(i + 2) * NCOL)[t];
            if (i & 1) cb1 = nx; else cb0 = nx;
        }

        float4 p = reinterpret_cast<const float4*>(Dprev)[t];
        float pm1 = (t == 0) ? ((i == 0) ? 0.0f : INFV) : Dprev[4 * t - 1];
        float a0 = c0 + fminf(p.x, pm1);
        float a1 = c1 + fminf(p.y, p.x);
        float a2 = c2 + fminf(p.z, p.y);
        float a3 = c3 + fminf(p.w, p.z);

        // thread-local combine of 4 elements
        float S = c0, M = a0;
        S += c1; M = fminf(M + c1, a1);
        S += c2; M = fminf(M + c2, a2);
        S += c3; M = fminf(M + c3, a3);

        // wave-inclusive scan (non-commutative op; prefix comes from lower lanes)
        float Sv = S, Mv = M;
        #pragma unroll
        for (int d = 1; d < 64; d <<= 1) {
            float So = __shfl_up(Sv, d, 64);
            float Mo = __shfl_up(Mv, d, 64);
            if (lane >= d) { Mv = fminf(Mo + Sv, Mv); Sv = So + Sv; }
        }
        float Sl = __shfl_up(Sv, 1, 64);   // lane-exclusive (valid for lane>0)
        float Ml = __shfl_up(Mv, 1, 64);

        if (lane == 63) wpair[wave] = make_float2(Sv, Mv);
        __syncthreads();   // wpair visible; all Dprev reads complete

        // exclusive prefix: waves before me, then lanes before me
        float Se = 0.0f, Me = INFV;
        for (int w2 = 0; w2 < wave; ++w2) {
            float2 W = wpair[w2];
            Me = fminf(Me + W.x, W.y);
            Se += W.x;
        }
        if (lane > 0) { Me = fminf(Me + Sl, Ml); Se += Sl; }

        // reconstruct the 4 outputs
        float Sr = Se, Mr = Me;
        Sr += c0; Mr = fminf(Mr + c0, a0); float d0 = Mr;
        Sr += c1; Mr = fminf(Mr + c1, a1); float d1 = Mr;
        Sr += c2; Mr = fminf(Mr + c2, a2); float d2 = Mr;
        Sr += c3; Mr = fminf(Mr + c3, a3); float d3 = Mr;

        reinterpret_cast<float4*>(Dprev)[t] = make_float4(d0, d1, d2, d3);
        Dlast = d3;
        __syncthreads();   // Dprev ready for next row
    }

    if (t == 1023) out[0] = 1.0f / (1.0f + Dlast);
}

// ---------------------------------------------------------------------------
extern "C" void kernel_launch(void* const* d_in, const int* in_sizes, int n_in,
                              void* d_out, int out_size, void* d_ws, size_t ws_size,
                              hipStream_t stream)
{
    const float* t1 = (const float*)d_in[0];
    const float* t2 = (const float*)d_in[1];
    float* out = (float*)d_out;

    char* ws = (char*)d_ws;
    unsigned short* t1n  = (unsigned short*)ws;                                   // 8 MB
    unsigned short* t2n  = (unsigned short*)(ws + (size_t)NROW * KDIM * 2);       // 8 MB
    unsigned short* cost = (unsigned short*)(ws + (size_t)2 * NROW * KDIM * 2);   // 32 MB

    normalize_bf16<<<2 * NROW, 256, 0, stream>>>(t1, t2, t1n, t2n);
    gemm_cost<<<dim3(NCOL / BM, NROW / BM), 256, 0, stream>>>(t1n, t2n, cost);
    dtw_kernel<<<1, 1024, 0, stream>>>(cost, out);
}

// Round 2
// 946.764 us; speedup vs baseline: 7.6092x; 7.6092x over previous
//
#include <hip/hip_runtime.h>
#include <hip/hip_bf16.h>
#include <stdint.h>

#define KDIM 1024
#define NROW 4096
#define NCOL 4096
#define INFV 1e30f
#define BM 128
#define BK 32
#define NWG 16            // 16 workgroups x 1 wave x 64 lanes x 4 cols = 4096 columns
#define PF 16             // prefetch depth (steps) for cost rows and boundary slots
#define NT (NROW + 64)    // total systolic steps per wave (multiple of PF)

typedef __bf16 bf16x8 __attribute__((ext_vector_type(8)));
typedef float f32x4 __attribute__((ext_vector_type(4)));

__device__ __forceinline__ unsigned short f2bf(float f) {
    __hip_bfloat16 h = __float2bfloat16(f);
    return *reinterpret_cast<unsigned short*>(&h);
}

// ---------------------------------------------------------------------------
// Kernel 1: row-normalize both trajectories, emit bf16
// ---------------------------------------------------------------------------
__global__ __launch_bounds__(256) void normalize_bf16(
    const float* __restrict__ t1, const float* __restrict__ t2,
    unsigned short* __restrict__ o1, unsigned short* __restrict__ o2)
{
    int b = blockIdx.x;
    int t = threadIdx.x;
    const float* src;
    unsigned short* dst;
    if (b < NROW) { src = t1 + (size_t)b * KDIM;          dst = o1 + (size_t)b * KDIM; }
    else          { src = t2 + (size_t)(b - NROW) * KDIM; dst = o2 + (size_t)(b - NROW) * KDIM; }

    float4 v = reinterpret_cast<const float4*>(src)[t];
    float ss = v.x * v.x + v.y * v.y + v.z * v.z + v.w * v.w;
    #pragma unroll
    for (int d = 32; d >= 1; d >>= 1) ss += __shfl_xor(ss, d, 64);

    __shared__ float wsum[4];
    int wave = t >> 6;
    if ((t & 63) == 0) wsum[wave] = ss;
    __syncthreads();
    float inv = 1.0f / (sqrtf(wsum[0] + wsum[1] + wsum[2] + wsum[3]) + 1e-8f);

    ushort4 o;
    o.x = f2bf(v.x * inv);
    o.y = f2bf(v.y * inv);
    o.z = f2bf(v.z * inv);
    o.w = f2bf(v.w * inv);
    reinterpret_cast<ushort4*>(dst)[t] = o;
}

// ---------------------------------------------------------------------------
// Kernel 2: cost[i][j] = 1 - dot(t1n[i], t2n[j])  (bf16 in, bf16 out)
// 128x128 tile, BK=32, 4 waves each owning a 64x64 quadrant (4x4 of 16x16).
// ---------------------------------------------------------------------------
__global__ __launch_bounds__(256) void gemm_cost(
    const unsigned short* __restrict__ A,
    const unsigned short* __restrict__ B,
    unsigned short* __restrict__ C)
{
    __shared__ __align__(16) unsigned short As[BM * BK];
    __shared__ __align__(16) unsigned short Bs[BM * BK];

    int t    = threadIdx.x;
    int lane = t & 63;
    int wave = t >> 6;
    int i0   = blockIdx.y * BM;
    int j0   = blockIdx.x * BM;

    f32x4 acc[4][4];
    f32x4 zero = {0.f, 0.f, 0.f, 0.f};
    #pragma unroll
    for (int m = 0; m < 4; ++m)
        #pragma unroll
        for (int n = 0; n < 4; ++n) acc[m][n] = zero;

    int frow = lane & 15;
    int fk   = (lane >> 4) * 8;
    int wr   = (wave >> 1) * 64;
    int wc   = (wave & 1) * 64;

    int srow = t >> 2;
    int scb  = (t & 3) * 8;

    uint4 ra0, ra1, rb0, rb1;
    {
        ra0 = *reinterpret_cast<const uint4*>(A + (size_t)(i0 + srow) * KDIM + scb);
        ra1 = *reinterpret_cast<const uint4*>(A + (size_t)(i0 + 64 + srow) * KDIM + scb);
        rb0 = *reinterpret_cast<const uint4*>(B + (size_t)(j0 + srow) * KDIM + scb);
        rb1 = *reinterpret_cast<const uint4*>(B + (size_t)(j0 + 64 + srow) * KDIM + scb);
    }

    for (int k0 = 0; k0 < KDIM; k0 += BK) {
        __syncthreads();
        *reinterpret_cast<uint4*>(As + (size_t)t * 8)         = ra0;
        *reinterpret_cast<uint4*>(As + (size_t)(256 + t) * 8) = ra1;
        *reinterpret_cast<uint4*>(Bs + (size_t)t * 8)         = rb0;
        *reinterpret_cast<uint4*>(Bs + (size_t)(256 + t) * 8) = rb1;
        __syncthreads();

        if (k0 + BK < KDIM) {
            int kn = k0 + BK;
            ra0 = *reinterpret_cast<const uint4*>(A + (size_t)(i0 + srow) * KDIM + kn + scb);
            ra1 = *reinterpret_cast<const uint4*>(A + (size_t)(i0 + 64 + srow) * KDIM + kn + scb);
            rb0 = *reinterpret_cast<const uint4*>(B + (size_t)(j0 + srow) * KDIM + kn + scb);
            rb1 = *reinterpret_cast<const uint4*>(B + (size_t)(j0 + 64 + srow) * KDIM + kn + scb);
        }

        bf16x8 af[4], bfr[4];
        #pragma unroll
        for (int m = 0; m < 4; ++m)
            af[m] = *reinterpret_cast<const bf16x8*>(As + (wr + m * 16 + frow) * BK + fk);
        #pragma unroll
        for (int n = 0; n < 4; ++n)
            bfr[n] = *reinterpret_cast<const bf16x8*>(Bs + (wc + n * 16 + frow) * BK + fk);

        #pragma unroll
        for (int m = 0; m < 4; ++m)
            #pragma unroll
            for (int n = 0; n < 4; ++n)
                acc[m][n] = __builtin_amdgcn_mfma_f32_16x16x32_bf16(af[m], bfr[n], acc[m][n], 0, 0, 0);
    }

    int crow = (lane >> 4) * 4;
    int ccol = lane & 15;
    #pragma unroll
    for (int m = 0; m < 4; ++m)
        #pragma unroll
        for (int n = 0; n < 4; ++n) {
            size_t base = (size_t)(i0 + wr + m * 16 + crow) * NCOL + (j0 + wc + n * 16 + ccol);
            #pragma unroll
            for (int q = 0; q < 4; ++q)
                C[base + (size_t)q * NCOL] = f2bf(1.0f - acc[m][n][q]);
        }
}

// ---------------------------------------------------------------------------
// Kernel 3: lane-skewed systolic DTW.
// 16 WGs x 1 wave; lane L of WG w owns columns [4*(64w+L), +4).
// Step t: lane computes row r = t - L (4-cell min3 chain), passes right
// boundary to lane+1 via shfl_up. WG boundary: (tag,value) packed in one
// 8-byte device-scope atomic slot per row (unique slots, memset-cleared),
// consumer keeps a PF-deep register prefetch queue -> zero steady-state polls.
// ---------------------------------------------------------------------------
__global__ __launch_bounds__(64) void dtw_systolic(
    const unsigned short* __restrict__ cost,
    unsigned long long* __restrict__ ring,   // [NWG-1][NROW] (tag=row+1 | valbits<<32)
    float* __restrict__ out)
{
    const int w    = blockIdx.x;
    const int lane = threadIdx.x;
    const char* cb = (const char*)cost;
    const size_t colByte = (size_t)(w * 512 + lane * 8);   // 4 bf16 = 8B per lane

    uint2 cq[PF];                 // cost prefetch queue
    unsigned long long bq[PF];    // boundary prefetch queue (lane 0 only meaningful)

    #pragma unroll
    for (int p = 0; p < PF; ++p) {
        int rr = p - lane; rr = rr < 0 ? 0 : rr;
        cq[p] = *reinterpret_cast<const uint2*>(cb + ((size_t)rr << 13) + colByte);
    }
    if (w > 0 && lane == 0) {
        #pragma unroll
        for (int p = 0; p < PF; ++p)
            bq[p] = __hip_atomic_load(ring + (size_t)(w - 1) * NROW + p,
                                      __ATOMIC_RELAXED, __HIP_MEMORY_SCOPE_AGENT);
    }

    float pd0 = INFV, pd1 = INFV, pd2 = INFV, pd3 = INFV;
    float ll = INFV, dl = INFV;
    float ans = 0.0f;

    for (int o = 0; o < NT / PF; ++o) {
        #pragma unroll
        for (int p = 0; p < PF; ++p) {
            const int t = o * PF + p;
            const uint2 cu = cq[p];

            // reissue cost prefetch: row t+PF-lane, clamped
            int rl = t + PF - lane;
            rl = rl < 0 ? 0 : rl;
            rl = rl > NROW - 1 ? NROW - 1 : rl;
            cq[p] = *reinterpret_cast<const uint2*>(cb + ((size_t)rl << 13) + colByte);

            // obtain left boundary for lane 0 (row t)
            if (w > 0 && t < NROW) {
                if (lane == 0) {
                    unsigned long long v = bq[p];
                    const unsigned expt = (unsigned)(t + 1);
                    if ((unsigned)v != expt) {
                        const unsigned long long* slot = ring + (size_t)(w - 1) * NROW + t;
                        do {
                            v = __hip_atomic_load(slot, __ATOMIC_RELAXED, __HIP_MEMORY_SCOPE_AGENT);
                        } while ((unsigned)v != expt);
                    }
                    ll = __uint_as_float((unsigned)(v >> 32));
                    int rb = t + PF; rb = rb > NROW - 1 ? NROW - 1 : rb;
                    bq[p] = __hip_atomic_load(ring + (size_t)(w - 1) * NROW + rb,
                                              __ATOMIC_RELAXED, __HIP_MEMORY_SCOPE_AGENT);
                }
            }
            if (w == 0 && lane == 0) { ll = INFV; dl = (t == 0) ? 0.0f : INFV; }

            const float c0 = __uint_as_float(cu.x << 16);
            const float c1 = __uint_as_float(cu.x & 0xffff0000u);
            const float c2 = __uint_as_float(cu.y << 16);
            const float c3 = __uint_as_float(cu.y & 0xffff0000u);

            const float d0 = c0 + fminf(fminf(ll, pd0), dl);
            const float d1 = c1 + fminf(fminf(d0, pd1), pd0);
            const float d2 = c2 + fminf(fminf(d1, pd2), pd1);
            const float d3 = c3 + fminf(fminf(d2, pd3), pd2);

            if (w < NWG - 1) {
                const int rp = t - 63;
                if ((unsigned)rp < (unsigned)NROW && lane == 63) {
                    unsigned long long pk =
                        ((unsigned long long)__float_as_uint(d3) << 32) | (unsigned)(rp + 1);
                    __hip_atomic_store(ring + (size_t)w * NROW + rp, pk,
                                       __ATOMIC_RELAXED, __HIP_MEMORY_SCOPE_AGENT);
                }
            } else {
                if (lane == 63 && t == NROW - 1 + 63) ans = d3;
            }

            const float nl = __shfl_up(d3, 1, 64);
            dl = ll;
            ll = nl;
            pd0 = d0; pd1 = d1; pd2 = d2; pd3 = d3;
        }
    }

    if (w == NWG - 1 && lane == 63) out[0] = 1.0f / (1.0f + ans);
}

// ---------------------------------------------------------------------------
extern "C" void kernel_launch(void* const* d_in, const int* in_sizes, int n_in,
                              void* d_out, int out_size, void* d_ws, size_t ws_size,
                              hipStream_t stream)
{
    const float* t1 = (const float*)d_in[0];
    const float* t2 = (const float*)d_in[1];
    float* out = (float*)d_out;

    char* ws = (char*)d_ws;
    unsigned short* t1n  = (unsigned short*)ws;                                   // 8 MB
    unsigned short* t2n  = (unsigned short*)(ws + (size_t)NROW * KDIM * 2);       // 8 MB
    unsigned short* cost = (unsigned short*)(ws + (size_t)2 * NROW * KDIM * 2);   // 32 MB
    unsigned long long* ring = (unsigned long long*)(ws + (size_t)48 * 1024 * 1024); // 480 KB

    hipMemsetAsync(ring, 0, (size_t)(NWG - 1) * NROW * 8, stream);
    normalize_bf16<<<2 * NROW, 256, 0, stream>>>(t1, t2, t1n, t2n);
    gemm_cost<<<dim3(NCOL / BM, NROW / BM), 256, 0, stream>>>(t1n, t2n, cost);
    dtw_systolic<<<NWG, 64, 0, stream>>>(cost, ring, out);
}